// Round 7
// baseline (560.337 us; speedup 1.0000x reference)
//
#include <hip/hip_runtime.h>
#include <hip/hip_bf16.h>
#include <math.h>

// ---------------------------------------------------------------------------
// DriverGeneGNN: 2-slice GCN (64->64->128) + BN + residual + MLP head.
// N=50000, E=1600000, fp32 compute, bf16 gather tables.
// R7: (a) GEMM A-tiles staged transposed with stride 65 (was 64): transpose
//     writes go 16-way -> 2-way (free); fragment reads scalar (broadcast,
//     conflict-free; b128 impossible at odd stride). (b) gather uses 8
//     lanes/node with 16B uint4 loads (8 bf16/lane).
// CSR build: 2-pass bucket sort (R5). Conv biases cancel in BN -> skipped.
// ---------------------------------------------------------------------------

__device__ __forceinline__ float sanf(float v) {
    if (v != v) return 0.f;
    if (isinf(v)) return v > 0.f ? 100.f : -100.f;
    return v;
}

__device__ __forceinline__ unsigned short bf16of(float v) {
    __hip_bfloat16 h = __float2bfloat16(v);
    return *(unsigned short*)&h;
}
__device__ __forceinline__ float uflo(unsigned u) { return __uint_as_float(u << 16); }
__device__ __forceinline__ float ufhi(unsigned u) { return __uint_as_float(u & 0xFFFF0000u); }

// --- CSR build: 2-pass bucket sort (unchanged from R5) ----------------------

__global__ __launch_bounds__(256) void kA_buckhist(const int* __restrict__ ei0,
                                                   const int* __restrict__ ei1,
                                                   int* __restrict__ bcnt,
                                                   int E, int n, int NB) {
    __shared__ int h[512];
    for (int i = threadIdx.x; i < 512; i += 256) h[i] = 0;
    __syncthreads();
    int E2 = 2 * E, stride = gridDim.x * 256;
    for (int ge = blockIdx.x * 256 + threadIdx.x; ge < E2; ge += stride) {
        int slice = ge >= E;
        const int* ei = slice ? ei1 : ei0;
        int e = ge - slice * E;
        int gcol = slice * n + ei[E + e];
        atomicAdd(&h[gcol >> 8], 1);
    }
    __syncthreads();
    for (int b = threadIdx.x; b < NB; b += 256)
        if (h[b]) atomicAdd(&bcnt[b], h[b]);
}

__global__ __launch_bounds__(256) void kB_scan(const int* __restrict__ bcnt,
                                               int* __restrict__ bstart,
                                               int* __restrict__ bcur, int NB, int E2) {
    __shared__ int tmp[256];
    int t = threadIdx.x, carry = 0;
    for (int base = 0; base < NB; base += 256) {
        int i = base + t;
        int v = (i < NB) ? bcnt[i] : 0;
        tmp[t] = v;
        __syncthreads();
        for (int off = 1; off < 256; off <<= 1) {
            int u = (t >= off) ? tmp[t - off] : 0;
            __syncthreads();
            tmp[t] += u;
            __syncthreads();
        }
        if (i < NB) {
            int ex = tmp[t] - v + carry;
            bstart[i] = ex;
            bcur[i] = ex;
        }
        carry += tmp[255];
        __syncthreads();
    }
    if (t == 0) bstart[NB] = E2;
}

__global__ __launch_bounds__(256) void kC_bin(const int* __restrict__ ei0,
                                              const int* __restrict__ ei1,
                                              int* __restrict__ bcur,
                                              unsigned* __restrict__ binned,
                                              int E, int n, int chunk) {
    __shared__ int cnt[512];
    __shared__ int base[512];
    for (int i = threadIdx.x; i < 512; i += 256) cnt[i] = 0;
    __syncthreads();
    int E2 = 2 * E;
    int e0 = blockIdx.x * chunk, e1 = min(e0 + chunk, E2);
    for (int ge = e0 + threadIdx.x; ge < e1; ge += 256) {
        int slice = ge >= E;
        const int* ei = slice ? ei1 : ei0;
        int e = ge - slice * E;
        int gcol = slice * n + ei[E + e];
        atomicAdd(&cnt[gcol >> 8], 1);
    }
    __syncthreads();
    for (int b = threadIdx.x; b < 512; b += 256) {
        int c = cnt[b];
        base[b] = c ? atomicAdd(&bcur[b], c) : 0;
    }
    __syncthreads();
    for (int i = threadIdx.x; i < 512; i += 256) cnt[i] = 0;
    __syncthreads();
    for (int ge = e0 + threadIdx.x; ge < e1; ge += 256) {
        int slice = ge >= E;
        const int* ei = slice ? ei1 : ei0;
        int e = ge - slice * E;
        int col = ei[E + e], row = ei[e];
        int gcol = slice * n + col;
        int b = gcol >> 8;
        int loc = atomicAdd(&cnt[b], 1);
        binned[base[b] + loc] = (unsigned)row | (((unsigned)gcol & 255u) << 17);
    }
}

__global__ __launch_bounds__(256) void kD_build(const unsigned* __restrict__ binned,
                                                const int* __restrict__ bstart,
                                                int* __restrict__ rowptr,
                                                float* __restrict__ dinv,
                                                int* __restrict__ csr,
                                                int n2, int E2) {
    __shared__ int cnt[256];
    __shared__ int scn[256];
    __shared__ int cur[256];
    int b = blockIdx.x, t = threadIdx.x;
    int s = bstart[b], e = bstart[b + 1];
    cnt[t] = 0;
    __syncthreads();
    for (int i = s + t; i < e; i += 256) atomicAdd(&cnt[(binned[i] >> 17) & 255], 1);
    __syncthreads();
    int v = cnt[t];
    scn[t] = v;
    __syncthreads();
    for (int off = 1; off < 256; off <<= 1) {
        int u = (t >= off) ? scn[t - off] : 0;
        __syncthreads();
        scn[t] += u;
        __syncthreads();
    }
    int excl = scn[t] - v;
    int gcol = b * 256 + t;
    if (gcol < n2) {
        rowptr[gcol] = s + excl;
        dinv[gcol] = v > 0 ? rsqrtf((float)v) : 0.f;
    }
    cur[t] = excl;
    __syncthreads();
    for (int i = s + t; i < e; i += 256) {
        unsigned p = binned[i];
        int cl = (p >> 17) & 255;
        int pos = s + atomicAdd(&cur[cl], 1);
        csr[pos] = (int)(p & 0x1FFFFu);
    }
    if (b == 0 && t == 0) rowptr[n2] = E2;
}

// --- gather path (bf16 tables, 8 lanes/node, 16B loads) ---------------------

__global__ __launch_bounds__(256) void prescale_bf(const float* __restrict__ x,
                                                   const float* __restrict__ dinv,
                                                   unsigned short* __restrict__ xsb,
                                                   int n64, int n) {
    int i = blockIdx.x * 256 + threadIdx.x;
    if (i >= n64) return;
    int row = i >> 6;
    float v = x[i];
    xsb[i] = bf16of(v * dinv[row]);
    xsb[n64 + i] = bf16of(v * dinv[n + row]);
}

__global__ __launch_bounds__(256) void gatherbf_kernel(const int* __restrict__ rowptr,
                                                       const int* __restrict__ csr,
                                                       const unsigned short* __restrict__ m,
                                                       const float* __restrict__ dinv,
                                                       float* __restrict__ out, int n, int n2) {
    int gid = blockIdx.x * 256 + threadIdx.x;
    int node = gid >> 3;
    if (node >= n2) return;
    int l = threadIdx.x & 7;
    const unsigned short* mb = m + (size_t)((node >= n) ? n : 0) * 64;
    int s = rowptr[node], e = rowptr[node + 1];
    float a0 = 0.f, a1 = 0.f, a2 = 0.f, a3 = 0.f, a4 = 0.f, a5 = 0.f, a6 = 0.f, a7 = 0.f;
    for (int b = s; b < e; b += 8) {
        int cntn = min(8, e - b);
        int idx = (b + l < e) ? csr[b + l] : 0;
        int j = 0;
        for (; j + 4 <= cntn; j += 4) {
            int r0 = __shfl(idx, j + 0, 8);
            int r1 = __shfl(idx, j + 1, 8);
            int r2 = __shfl(idx, j + 2, 8);
            int r3 = __shfl(idx, j + 3, 8);
            uint4 u0 = *(const uint4*)&mb[(size_t)r0 * 64 + l * 8];
            uint4 u1 = *(const uint4*)&mb[(size_t)r1 * 64 + l * 8];
            uint4 u2 = *(const uint4*)&mb[(size_t)r2 * 64 + l * 8];
            uint4 u3 = *(const uint4*)&mb[(size_t)r3 * 64 + l * 8];
            a0 += (uflo(u0.x) + uflo(u1.x)) + (uflo(u2.x) + uflo(u3.x));
            a1 += (ufhi(u0.x) + ufhi(u1.x)) + (ufhi(u2.x) + ufhi(u3.x));
            a2 += (uflo(u0.y) + uflo(u1.y)) + (uflo(u2.y) + uflo(u3.y));
            a3 += (ufhi(u0.y) + ufhi(u1.y)) + (ufhi(u2.y) + ufhi(u3.y));
            a4 += (uflo(u0.z) + uflo(u1.z)) + (uflo(u2.z) + uflo(u3.z));
            a5 += (ufhi(u0.z) + ufhi(u1.z)) + (ufhi(u2.z) + ufhi(u3.z));
            a6 += (uflo(u0.w) + uflo(u1.w)) + (uflo(u2.w) + uflo(u3.w));
            a7 += (ufhi(u0.w) + ufhi(u1.w)) + (ufhi(u2.w) + ufhi(u3.w));
        }
        for (; j < cntn; ++j) {
            int r = __shfl(idx, j, 8);
            uint4 u = *(const uint4*)&mb[(size_t)r * 64 + l * 8];
            a0 += uflo(u.x); a1 += ufhi(u.x);
            a2 += uflo(u.y); a3 += ufhi(u.y);
            a4 += uflo(u.z); a5 += ufhi(u.z);
            a6 += uflo(u.w); a7 += ufhi(u.w);
        }
    }
    float d = dinv[node];
    float4 o0 = {a0 * d, a1 * d, a2 * d, a3 * d};
    float4 o1 = {a4 * d, a5 * d, a6 * d, a7 * d};
    *(float4*)&out[(size_t)node * 64 + l * 8] = o0;
    *(float4*)&out[(size_t)node * 64 + l * 8 + 4] = o1;
}

// --- dense path: 64-row-tile GEMMs, As stride 65 ----------------------------

template <int F>
__global__ __launch_bounds__(256) void gemmb_kernel(const float* __restrict__ A,
                                                    const float* __restrict__ W0,
                                                    const float* __restrict__ W1,
                                                    float* __restrict__ C, int n) {
    constexpr int NC = F / 64;
    __shared__ float Ws[64 * F];
    __shared__ float As[64 * 65];  // transposed, stride 65: As[k*65 + row]
    int BPS = (n + 63) >> 6;
    int slice = blockIdx.x >= BPS;
    int sb = blockIdx.x - slice * BPS;
    const float* W = slice ? W1 : W0;
    int row0 = slice * n + sb * 64;
    int rows = min(64, n - sb * 64);
    for (int i = threadIdx.x; i < 64 * F; i += 256) Ws[i] = W[i];
    for (int idx = threadIdx.x; idx < 1024; idx += 256) {
        int r = idx >> 4, kc = (idx & 15) * 4;
        float4 v = {0.f, 0.f, 0.f, 0.f};
        if (r < rows) v = *(const float4*)&A[(size_t)(row0 + r) * 64 + kc];
        As[(kc + 0) * 65 + r] = v.x;
        As[(kc + 1) * 65 + r] = v.y;
        As[(kc + 2) * 65 + r] = v.z;
        As[(kc + 3) * 65 + r] = v.w;
    }
    __syncthreads();
    int tx = threadIdx.x & 15, ty = threadIdx.x >> 4;
    float4 acc[4][NC];
#pragma unroll
    for (int i = 0; i < 4; ++i)
#pragma unroll
        for (int j = 0; j < NC; ++j) acc[i][j] = {0.f, 0.f, 0.f, 0.f};
    for (int k = 0; k < 64; ++k) {
        const float* ap = &As[k * 65 + ty * 4];
#pragma unroll
        for (int j = 0; j < NC; ++j) {
            float4 wv = *(const float4*)&Ws[k * F + j * 64 + tx * 4];
#pragma unroll
            for (int i = 0; i < 4; ++i) {
                acc[i][j].x = fmaf(ap[i], wv.x, acc[i][j].x);
                acc[i][j].y = fmaf(ap[i], wv.y, acc[i][j].y);
                acc[i][j].z = fmaf(ap[i], wv.z, acc[i][j].z);
                acc[i][j].w = fmaf(ap[i], wv.w, acc[i][j].w);
            }
        }
    }
#pragma unroll
    for (int i = 0; i < 4; ++i) {
        int r = ty * 4 + i;
        if (r < rows)
#pragma unroll
            for (int j = 0; j < NC; ++j)
                *(float4*)&C[(size_t)(row0 + r) * F + j * 64 + tx * 4] = acc[i][j];
    }
}

template <int F>
__global__ __launch_bounds__(256) void bnstats_kernel(const float* __restrict__ h,
                                                      float* __restrict__ sums, int n, int bps) {
    constexpr int TPF = 256 / F;
    constexpr int ROWS = 128;
    __shared__ float l1[256], l2[256];
    int slice = blockIdx.x >= bps;
    int sb = blockIdx.x - slice * bps;
    int f = threadIdx.x & (F - 1);
    int sub = threadIdx.x / F;
    int r0 = slice * n + sb * ROWS;
    int rend = min(slice * n + n, r0 + ROWS);
    float s1 = 0.f, s2 = 0.f;
    for (int r = r0 + sub; r < rend; r += TPF) {
        float v = h[(size_t)r * F + f];
        s1 += v;
        s2 += v * v;
    }
    l1[threadIdx.x] = s1;
    l2[threadIdx.x] = s2;
    __syncthreads();
    if (threadIdx.x < F) {
#pragma unroll
        for (int i = 1; i < TPF; ++i) {
            s1 += l1[threadIdx.x + i * F];
            s2 += l2[threadIdx.x + i * F];
        }
        unsafeAtomicAdd(&sums[slice * 2 * F + threadIdx.x], s1);
        unsafeAtomicAdd(&sums[slice * 2 * F + F + threadIdx.x], s2);
    }
}

template <int F>
__global__ void bnfinal_kernel(const float* __restrict__ sums, const float* __restrict__ g,
                               const float* __restrict__ be, float* __restrict__ scsh, int n) {
    int f = threadIdx.x;
    if (f >= F) return;
    int slice = blockIdx.x;
    float inv_n = 1.0f / (float)n;
    float mu = sums[slice * 2 * F + f] * inv_n;
    float var = fmaxf(sums[slice * 2 * F + F + f] * inv_n - mu * mu, 0.f);
    float scale = g[f] * rsqrtf(var + 1e-5f);
    scsh[slice * 2 * F + f] = scale;
    scsh[slice * 2 * F + F + f] = be[f] - mu * scale;
}

__global__ __launch_bounds__(256) void apply0_kernel(const float* __restrict__ t0,
                                                     const float* __restrict__ x,
                                                     const float* __restrict__ scsh,
                                                     const float* __restrict__ dinv,
                                                     float* __restrict__ h1,
                                                     unsigned short* __restrict__ h1sb,
                                                     int n64, int total) {
    int i = blockIdx.x * 256 + threadIdx.x;
    if (i >= total) return;
    int slice = i >= n64;
    int f = i & 63;
    const float* sc = scsh + slice * 128;
    float v = fmaf(t0[i], sc[f], sc[64 + f]);
    v = fmaxf(v, 0.f) + x[i - slice * n64];
    v = sanf(v);
    h1[i] = v;
    h1sb[i] = bf16of(v * dinv[i >> 6]);
}

// fused: proj = h1 @ res1_slice, comb = san(bn(t1) + proj).  64-row tiles.
__global__ __launch_bounds__(256) void apply1_kernel(const float* __restrict__ T,
                                                     const float* __restrict__ H,
                                                     const float* __restrict__ res0,
                                                     const float* __restrict__ res1,
                                                     const float* __restrict__ scsh,
                                                     float* __restrict__ comb, int n) {
    __shared__ float Ws[64 * 128];
    __shared__ float As[64 * 65];
    int BPS = (n + 63) >> 6;
    int slice = blockIdx.x >= BPS;
    int sb = blockIdx.x - slice * BPS;
    const float* res = slice ? res1 : res0;
    int row0 = slice * n + sb * 64;
    int rows = min(64, n - sb * 64);
    for (int i = threadIdx.x; i < 64 * 128; i += 256) Ws[i] = res[i];
    for (int idx = threadIdx.x; idx < 1024; idx += 256) {
        int r = idx >> 4, kc = (idx & 15) * 4;
        float4 v = {0.f, 0.f, 0.f, 0.f};
        if (r < rows) v = *(const float4*)&H[(size_t)(row0 + r) * 64 + kc];
        As[(kc + 0) * 65 + r] = v.x;
        As[(kc + 1) * 65 + r] = v.y;
        As[(kc + 2) * 65 + r] = v.z;
        As[(kc + 3) * 65 + r] = v.w;
    }
    __syncthreads();
    int tx = threadIdx.x & 15, ty = threadIdx.x >> 4;
    float4 acc[4][2];
#pragma unroll
    for (int i = 0; i < 4; ++i) {
        acc[i][0] = {0.f, 0.f, 0.f, 0.f};
        acc[i][1] = {0.f, 0.f, 0.f, 0.f};
    }
    for (int k = 0; k < 64; ++k) {
        const float* ap = &As[k * 65 + ty * 4];
        float4 w0 = *(const float4*)&Ws[k * 128 + tx * 4];
        float4 w1 = *(const float4*)&Ws[k * 128 + 64 + tx * 4];
#pragma unroll
        for (int i = 0; i < 4; ++i) {
            acc[i][0].x = fmaf(ap[i], w0.x, acc[i][0].x);
            acc[i][0].y = fmaf(ap[i], w0.y, acc[i][0].y);
            acc[i][0].z = fmaf(ap[i], w0.z, acc[i][0].z);
            acc[i][0].w = fmaf(ap[i], w0.w, acc[i][0].w);
            acc[i][1].x = fmaf(ap[i], w1.x, acc[i][1].x);
            acc[i][1].y = fmaf(ap[i], w1.y, acc[i][1].y);
            acc[i][1].z = fmaf(ap[i], w1.z, acc[i][1].z);
            acc[i][1].w = fmaf(ap[i], w1.w, acc[i][1].w);
        }
    }
    const float* sc = scsh + slice * 256;
#pragma unroll
    for (int i = 0; i < 4; ++i) {
        int r = ty * 4 + i;
        if (r >= rows) continue;
        int row = row0 + r;
        int lrow = row - slice * n;
#pragma unroll
        for (int j = 0; j < 2; ++j) {
            int c = j * 64 + tx * 4;
            float4 tv = *(const float4*)&T[(size_t)row * 128 + c];
            float4 o;
            o.x = sanf(fmaf(tv.x, sc[c + 0], sc[128 + c + 0]) + acc[i][j].x);
            o.y = sanf(fmaf(tv.y, sc[c + 1], sc[128 + c + 1]) + acc[i][j].y);
            o.z = sanf(fmaf(tv.z, sc[c + 2], sc[128 + c + 2]) + acc[i][j].z);
            o.w = sanf(fmaf(tv.w, sc[c + 3], sc[128 + c + 3]) + acc[i][j].w);
            *(float4*)&comb[(size_t)lrow * 256 + slice * 128 + c] = o;
        }
    }
}

// h[n,128] = relu(comb[n,256] @ w[256,128] + bias).  64-row tiles, 4 k-tiles.
__global__ __launch_bounds__(256) void head_gemm(const float* __restrict__ comb,
                                                 const float* __restrict__ w,
                                                 const float* __restrict__ bias,
                                                 float* __restrict__ h, int n) {
    __shared__ float Ws[64 * 128];
    __shared__ float As[64 * 65];
    int row0 = blockIdx.x * 64;
    int rows = min(64, n - row0);
    int tx = threadIdx.x & 15, ty = threadIdx.x >> 4;
    float4 acc[4][2];
#pragma unroll
    for (int i = 0; i < 4; ++i) {
        acc[i][0] = {0.f, 0.f, 0.f, 0.f};
        acc[i][1] = {0.f, 0.f, 0.f, 0.f};
    }
    for (int kt = 0; kt < 256; kt += 64) {
        for (int i = threadIdx.x; i < 64 * 128; i += 256) Ws[i] = w[(size_t)kt * 128 + i];
        for (int idx = threadIdx.x; idx < 1024; idx += 256) {
            int r = idx >> 4, kc = (idx & 15) * 4;
            float4 v = {0.f, 0.f, 0.f, 0.f};
            if (r < rows) v = *(const float4*)&comb[(size_t)(row0 + r) * 256 + kt + kc];
            As[(kc + 0) * 65 + r] = v.x;
            As[(kc + 1) * 65 + r] = v.y;
            As[(kc + 2) * 65 + r] = v.z;
            As[(kc + 3) * 65 + r] = v.w;
        }
        __syncthreads();
        for (int k = 0; k < 64; ++k) {
            const float* ap = &As[k * 65 + ty * 4];
            float4 w0 = *(const float4*)&Ws[k * 128 + tx * 4];
            float4 w1 = *(const float4*)&Ws[k * 128 + 64 + tx * 4];
#pragma unroll
            for (int i = 0; i < 4; ++i) {
                acc[i][0].x = fmaf(ap[i], w0.x, acc[i][0].x);
                acc[i][0].y = fmaf(ap[i], w0.y, acc[i][0].y);
                acc[i][0].z = fmaf(ap[i], w0.z, acc[i][0].z);
                acc[i][0].w = fmaf(ap[i], w0.w, acc[i][0].w);
                acc[i][1].x = fmaf(ap[i], w1.x, acc[i][1].x);
                acc[i][1].y = fmaf(ap[i], w1.y, acc[i][1].y);
                acc[i][1].z = fmaf(ap[i], w1.z, acc[i][1].z);
                acc[i][1].w = fmaf(ap[i], w1.w, acc[i][1].w);
            }
        }
        __syncthreads();
    }
#pragma unroll
    for (int j = 0; j < 2; ++j) {
        int c = j * 64 + tx * 4;
        float4 b4 = *(const float4*)&bias[c];
#pragma unroll
        for (int i = 0; i < 4; ++i) {
            int r = ty * 4 + i;
            if (r >= rows) continue;
            float4 o;
            o.x = fmaxf(acc[i][j].x + b4.x, 0.f);
            o.y = fmaxf(acc[i][j].y + b4.y, 0.f);
            o.z = fmaxf(acc[i][j].z + b4.z, 0.f);
            o.w = fmaxf(acc[i][j].w + b4.w, 0.f);
            *(float4*)&h[(size_t)(row0 + r) * 128 + c] = o;
        }
    }
}

__global__ __launch_bounds__(256) void fc2_softmax_kernel(const float* __restrict__ h,
                                                          const float* __restrict__ w2,
                                                          const float* __restrict__ b2,
                                                          float* __restrict__ out, int n) {
    int gid = blockIdx.x * 256 + threadIdx.x;
    int row = gid >> 6;
    int lane = threadIdx.x & 63;
    if (row >= n) return;
    const float* hr = h + (size_t)row * 128;
    float a = hr[lane], b = hr[lane + 64];
    float p0 = fmaf(a, w2[lane * 2], b * w2[(lane + 64) * 2]);
    float p1 = fmaf(a, w2[lane * 2 + 1], b * w2[(lane + 64) * 2 + 1]);
#pragma unroll
    for (int o = 32; o > 0; o >>= 1) {
        p0 += __shfl_down(p0, o);
        p1 += __shfl_down(p1, o);
    }
    if (lane == 0) {
        float l0 = p0 + b2[0], l1 = p1 + b2[1];
        float mx = fmaxf(l0, l1);
        float e0 = expf(l0 - mx), e1 = expf(l1 - mx);
        float inv = 1.0f / (e0 + e1);
        out[(size_t)row * 2] = l0;
        out[(size_t)row * 2 + 1] = l1;
        out[(size_t)2 * n + row * 2] = e0 * inv;
        out[(size_t)2 * n + row * 2 + 1] = e1 * inv;
    }
}

static inline int cdiv(int a, int b) { return (a + b - 1) / b; }

extern "C" void kernel_launch(void* const* d_in, const int* in_sizes, int n_in,
                              void* d_out, int out_size, void* d_ws, size_t ws_size,
                              hipStream_t stream) {
    const float* x       = (const float*)d_in[0];
    const int*   ei0     = (const int*)d_in[1];
    const int*   ei1     = (const int*)d_in[2];
    const float* w0_s0   = (const float*)d_in[3];
    const float* w1_s0   = (const float*)d_in[5];
    const float* res1_s0 = (const float*)d_in[7];
    const float* w0_s1   = (const float*)d_in[8];
    const float* w1_s1   = (const float*)d_in[10];
    const float* res1_s1 = (const float*)d_in[12];
    const float* bn_g0   = (const float*)d_in[13];
    const float* bn_b0   = (const float*)d_in[14];
    const float* bn_g1   = (const float*)d_in[15];
    const float* bn_b1   = (const float*)d_in[16];
    const float* fc1_w   = (const float*)d_in[17];
    const float* fc1_b   = (const float*)d_in[18];
    const float* fc2_w   = (const float*)d_in[19];
    const float* fc2_b   = (const float*)d_in[20];
    float* out = (float*)d_out;

    int n = in_sizes[0] / 64;   // 50000
    int E = in_sizes[1] / 2;    // 1600000
    int n2 = 2 * n, E2 = 2 * E;
    int n64 = n * 64;
    int NB = cdiv(n2, 256);     // 391 buckets
    int BPS = cdiv(n, 64);      // 782 row-tiles per slice

    float* X1   = (float*)d_ws;
    float* S    = X1 + (size_t)n2 * 64;
    float* G    = S + (size_t)n2 * 64;
    float* H    = G + (size_t)n2 * 64;
    float* comb = H + (size_t)n2 * 64;
    float* dinv = comb + (size_t)n * 256;
    float* sums = dinv + n2;
    float* scsh = sums + 512;
    float* T    = X1;  // spans X1+S
    int* csr    = (int*)(scsh + 512);
    int* rowptr = csr + (size_t)E2;
    int* bcnt   = rowptr + (n2 + 1);
    int* bstart = bcnt + 512;
    int* bcur   = bstart + 513;
    unsigned* binned = (unsigned*)comb;           // dead before apply1 writes comb
    unsigned short* xsb  = (unsigned short*)H;    // dead before apply0 writes H
    unsigned short* h1sb = (unsigned short*)S;    // dead before gemmb128 writes T

    // --- CSR build (2-pass bucket sort) ---
    hipMemsetAsync(bcnt, 0, 512 * sizeof(int), stream);
    kA_buckhist<<<256, 256, 0, stream>>>(ei0, ei1, bcnt, E, n, NB);
    kB_scan<<<1, 256, 0, stream>>>(bcnt, bstart, bcur, NB, E2);
    kC_bin<<<cdiv(E2, 8192), 256, 0, stream>>>(ei0, ei1, bcur, binned, E, n, 8192);
    kD_build<<<NB, 256, 0, stream>>>(binned, bstart, rowptr, dinv, csr, n2, E2);

    // --- layer 0 (both slices): gather(bf16(dinv.x)) -> @W0 -> bn -> relu+x ---
    prescale_bf<<<cdiv(n64, 256), 256, 0, stream>>>(x, dinv, xsb, n64, n);
    gatherbf_kernel<<<cdiv(n2 * 8, 256), 256, 0, stream>>>(rowptr, csr, xsb, dinv, G, n, n2);
    gemmb_kernel<64><<<2 * BPS, 256, 0, stream>>>(G, w0_s0, w0_s1, X1, n);  // t0
    hipMemsetAsync(sums, 0, 256 * sizeof(float), stream);
    bnstats_kernel<64><<<2 * cdiv(n, 128), 256, 0, stream>>>(X1, sums, n, cdiv(n, 128));
    bnfinal_kernel<64><<<2, 64, 0, stream>>>(sums, bn_g0, bn_b0, scsh, n);
    apply0_kernel<<<cdiv(2 * n64, 256), 256, 0, stream>>>(X1, x, scsh, dinv, H, h1sb, n64, 2 * n64);

    // --- layer 1: gather(bf16(dinv.h1)) -> @W1 -> bn ; + h1@res1 fused ---
    gatherbf_kernel<<<cdiv(n2 * 8, 256), 256, 0, stream>>>(rowptr, csr, h1sb, dinv, G, n, n2);
    gemmb_kernel<128><<<2 * BPS, 256, 0, stream>>>(G, w1_s0, w1_s1, T, n);   // t1 -> X1+S
    hipMemsetAsync(sums, 0, 512 * sizeof(float), stream);
    bnstats_kernel<128><<<2 * cdiv(n, 128), 256, 0, stream>>>(T, sums, n, cdiv(n, 128));
    bnfinal_kernel<128><<<2, 128, 0, stream>>>(sums, bn_g1, bn_b1, scsh, n);
    apply1_kernel<<<2 * BPS, 256, 0, stream>>>(T, H, res1_s0, res1_s1, scsh, comb, n);

    // --- head ---
    head_gemm<<<BPS, 256, 0, stream>>>(comb, fc1_w, fc1_b, G, n);
    fc2_softmax_kernel<<<cdiv(n, 4), 256, 0, stream>>>(G, fc2_w, fc2_b, out, n);
}

// Round 8
// 458.356 us; speedup vs baseline: 1.2225x; 1.2225x over previous
//
#include <hip/hip_runtime.h>
#include <hip/hip_bf16.h>
#include <math.h>

// ---------------------------------------------------------------------------
// DriverGeneGNN: 2-slice GCN (64->64->128) + BN + residual + MLP head.
// N=50000, E=1600000. fp32 accumulate, bf16 operands for gathers + all GEMMs.
// R8: dense GEMMs (g@W0, g@W1, h1@res1, comb@fc1) moved to MFMA
//     (v_mfma_f32_16x16x32_bf16). 64-row tile/block, 4 waves x 16-row strip;
//     A,B staged in LDS as bf16-pairs with stride 36 u32 (144B: 16B-aligned
//     b128 frag reads, 2-way banks). Gather emits bf16; comb/hidden bf16.
// Frag layouts (HW-verified, guide S3): A[m=lane&15][k=(lane>>4)*8+j],
//     B[k][n=lane&15], C/D col=lane&15 row=(lane>>4)*4+reg.
// CSR build: 2-pass bucket sort. Conv biases cancel in BN -> skipped.
// ---------------------------------------------------------------------------

typedef short v8s __attribute__((ext_vector_type(8)));
typedef float f32x4 __attribute__((ext_vector_type(4)));

__device__ __forceinline__ float sanf(float v) {
    if (v != v) return 0.f;
    if (isinf(v)) return v > 0.f ? 100.f : -100.f;
    return v;
}

__device__ __forceinline__ unsigned short bf16of(float v) {
    __hip_bfloat16 h = __float2bfloat16(v);
    return *(unsigned short*)&h;
}
__device__ __forceinline__ unsigned pack2(float lo, float hi) {
    return (unsigned)bf16of(lo) | ((unsigned)bf16of(hi) << 16);
}
__device__ __forceinline__ float uflo(unsigned u) { return __uint_as_float(u << 16); }
__device__ __forceinline__ float ufhi(unsigned u) { return __uint_as_float(u & 0xFFFF0000u); }
__device__ __forceinline__ float fofbf16(unsigned short u) {
    return __uint_as_float(((unsigned)u) << 16);
}

// --- CSR build: 2-pass bucket sort ------------------------------------------

__global__ __launch_bounds__(256) void kA_buckhist(const int* __restrict__ ei0,
                                                   const int* __restrict__ ei1,
                                                   int* __restrict__ bcnt,
                                                   int E, int n, int NB) {
    __shared__ int h[512];
    for (int i = threadIdx.x; i < 512; i += 256) h[i] = 0;
    __syncthreads();
    int E2 = 2 * E, stride = gridDim.x * 256;
    for (int ge = blockIdx.x * 256 + threadIdx.x; ge < E2; ge += stride) {
        int slice = ge >= E;
        const int* ei = slice ? ei1 : ei0;
        int e = ge - slice * E;
        int gcol = slice * n + ei[E + e];
        atomicAdd(&h[gcol >> 8], 1);
    }
    __syncthreads();
    for (int b = threadIdx.x; b < NB; b += 256)
        if (h[b]) atomicAdd(&bcnt[b], h[b]);
}

__global__ __launch_bounds__(256) void kB_scan(const int* __restrict__ bcnt,
                                               int* __restrict__ bstart,
                                               int* __restrict__ bcur, int NB, int E2) {
    __shared__ int tmp[256];
    int t = threadIdx.x, carry = 0;
    for (int base = 0; base < NB; base += 256) {
        int i = base + t;
        int v = (i < NB) ? bcnt[i] : 0;
        tmp[t] = v;
        __syncthreads();
        for (int off = 1; off < 256; off <<= 1) {
            int u = (t >= off) ? tmp[t - off] : 0;
            __syncthreads();
            tmp[t] += u;
            __syncthreads();
        }
        if (i < NB) {
            int ex = tmp[t] - v + carry;
            bstart[i] = ex;
            bcur[i] = ex;
        }
        carry += tmp[255];
        __syncthreads();
    }
    if (t == 0) bstart[NB] = E2;
}

__global__ __launch_bounds__(256) void kC_bin(const int* __restrict__ ei0,
                                              const int* __restrict__ ei1,
                                              int* __restrict__ bcur,
                                              unsigned* __restrict__ binned,
                                              int E, int n, int chunk) {
    __shared__ int cnt[512];
    __shared__ int base[512];
    for (int i = threadIdx.x; i < 512; i += 256) cnt[i] = 0;
    __syncthreads();
    int E2 = 2 * E;
    int e0 = blockIdx.x * chunk, e1 = min(e0 + chunk, E2);
    for (int ge = e0 + threadIdx.x; ge < e1; ge += 256) {
        int slice = ge >= E;
        const int* ei = slice ? ei1 : ei0;
        int e = ge - slice * E;
        int gcol = slice * n + ei[E + e];
        atomicAdd(&cnt[gcol >> 8], 1);
    }
    __syncthreads();
    for (int b = threadIdx.x; b < 512; b += 256) {
        int c = cnt[b];
        base[b] = c ? atomicAdd(&bcur[b], c) : 0;
    }
    __syncthreads();
    for (int i = threadIdx.x; i < 512; i += 256) cnt[i] = 0;
    __syncthreads();
    for (int ge = e0 + threadIdx.x; ge < e1; ge += 256) {
        int slice = ge >= E;
        const int* ei = slice ? ei1 : ei0;
        int e = ge - slice * E;
        int col = ei[E + e], row = ei[e];
        int gcol = slice * n + col;
        int b = gcol >> 8;
        int loc = atomicAdd(&cnt[b], 1);
        binned[base[b] + loc] = (unsigned)row | (((unsigned)gcol & 255u) << 17);
    }
}

__global__ __launch_bounds__(256) void kD_build(const unsigned* __restrict__ binned,
                                                const int* __restrict__ bstart,
                                                int* __restrict__ rowptr,
                                                float* __restrict__ dinv,
                                                int* __restrict__ csr,
                                                int n2, int E2) {
    __shared__ int cnt[256];
    __shared__ int scn[256];
    __shared__ int cur[256];
    int b = blockIdx.x, t = threadIdx.x;
    int s = bstart[b], e = bstart[b + 1];
    cnt[t] = 0;
    __syncthreads();
    for (int i = s + t; i < e; i += 256) atomicAdd(&cnt[(binned[i] >> 17) & 255], 1);
    __syncthreads();
    int v = cnt[t];
    scn[t] = v;
    __syncthreads();
    for (int off = 1; off < 256; off <<= 1) {
        int u = (t >= off) ? scn[t - off] : 0;
        __syncthreads();
        scn[t] += u;
        __syncthreads();
    }
    int excl = scn[t] - v;
    int gcol = b * 256 + t;
    if (gcol < n2) {
        rowptr[gcol] = s + excl;
        dinv[gcol] = v > 0 ? rsqrtf((float)v) : 0.f;
    }
    cur[t] = excl;
    __syncthreads();
    for (int i = s + t; i < e; i += 256) {
        unsigned p = binned[i];
        int cl = (p >> 17) & 255;
        int pos = s + atomicAdd(&cur[cl], 1);
        csr[pos] = (int)(p & 0x1FFFFu);
    }
    if (b == 0 && t == 0) rowptr[n2] = E2;
}

// --- gather path (bf16 in, bf16 out) ----------------------------------------

__global__ __launch_bounds__(256) void prescale_bf(const float* __restrict__ x,
                                                   const float* __restrict__ dinv,
                                                   unsigned short* __restrict__ xsb,
                                                   int n64, int n) {
    int i = blockIdx.x * 256 + threadIdx.x;
    if (i >= n64) return;
    int row = i >> 6;
    float v = x[i];
    xsb[i] = bf16of(v * dinv[row]);
    xsb[n64 + i] = bf16of(v * dinv[n + row]);
}

__global__ __launch_bounds__(256) void gatherbf_kernel(const int* __restrict__ rowptr,
                                                       const int* __restrict__ csr,
                                                       const unsigned short* __restrict__ m,
                                                       const float* __restrict__ dinv,
                                                       unsigned short* __restrict__ outb,
                                                       int n, int n2) {
    int gid = blockIdx.x * 256 + threadIdx.x;
    int node = gid >> 3;
    if (node >= n2) return;
    int l = threadIdx.x & 7;
    const unsigned short* mb = m + (size_t)((node >= n) ? n : 0) * 64;
    int s = rowptr[node], e = rowptr[node + 1];
    float a0 = 0.f, a1 = 0.f, a2 = 0.f, a3 = 0.f, a4 = 0.f, a5 = 0.f, a6 = 0.f, a7 = 0.f;
    for (int b = s; b < e; b += 8) {
        int cntn = min(8, e - b);
        int idx = (b + l < e) ? csr[b + l] : 0;
        int j = 0;
        for (; j + 4 <= cntn; j += 4) {
            int r0 = __shfl(idx, j + 0, 8);
            int r1 = __shfl(idx, j + 1, 8);
            int r2 = __shfl(idx, j + 2, 8);
            int r3 = __shfl(idx, j + 3, 8);
            uint4 u0 = *(const uint4*)&mb[(size_t)r0 * 64 + l * 8];
            uint4 u1 = *(const uint4*)&mb[(size_t)r1 * 64 + l * 8];
            uint4 u2 = *(const uint4*)&mb[(size_t)r2 * 64 + l * 8];
            uint4 u3 = *(const uint4*)&mb[(size_t)r3 * 64 + l * 8];
            a0 += (uflo(u0.x) + uflo(u1.x)) + (uflo(u2.x) + uflo(u3.x));
            a1 += (ufhi(u0.x) + ufhi(u1.x)) + (ufhi(u2.x) + ufhi(u3.x));
            a2 += (uflo(u0.y) + uflo(u1.y)) + (uflo(u2.y) + uflo(u3.y));
            a3 += (ufhi(u0.y) + ufhi(u1.y)) + (ufhi(u2.y) + ufhi(u3.y));
            a4 += (uflo(u0.z) + uflo(u1.z)) + (uflo(u2.z) + uflo(u3.z));
            a5 += (ufhi(u0.z) + ufhi(u1.z)) + (ufhi(u2.z) + ufhi(u3.z));
            a6 += (uflo(u0.w) + uflo(u1.w)) + (uflo(u2.w) + uflo(u3.w));
            a7 += (ufhi(u0.w) + ufhi(u1.w)) + (ufhi(u2.w) + ufhi(u3.w));
        }
        for (; j < cntn; ++j) {
            int r = __shfl(idx, j, 8);
            uint4 u = *(const uint4*)&mb[(size_t)r * 64 + l * 8];
            a0 += uflo(u.x); a1 += ufhi(u.x);
            a2 += uflo(u.y); a3 += ufhi(u.y);
            a4 += uflo(u.z); a5 += ufhi(u.z);
            a6 += uflo(u.w); a7 += ufhi(u.w);
        }
    }
    float d = dinv[node];
    uint4 o;
    o.x = pack2(a0 * d, a1 * d);
    o.y = pack2(a2 * d, a3 * d);
    o.z = pack2(a4 * d, a5 * d);
    o.w = pack2(a6 * d, a7 * d);
    *(uint4*)&outb[(size_t)node * 64 + l * 8] = o;
}

// --- MFMA GEMMs -------------------------------------------------------------
// Shared staging convention: As32[r][36] u32 (row r, k-pairs, 144B stride),
// Ws32[c][36] u32 (col c of W transposed).  Frag read = 16B at [*36 + s*16 + q*4].

// C[2n,F] fp32 = Ab[2n,64] @ W_slice[64,F]
template <int F>
__global__ __launch_bounds__(256) void mfma_gemmb(const unsigned short* __restrict__ Ab,
                                                  const float* __restrict__ W0,
                                                  const float* __restrict__ W1,
                                                  float* __restrict__ C, int n) {
    constexpr int NC = F / 16;
    __shared__ unsigned As32[64 * 36];
    __shared__ unsigned Ws32[F * 36];
    int BPS = (n + 63) >> 6;
    int slice = blockIdx.x >= BPS;
    int sb = blockIdx.x - slice * BPS;
    const float* W = slice ? W1 : W0;
    int row0 = slice * n + sb * 64;
    int rows = min(64, n - sb * 64);
    for (int idx = threadIdx.x; idx < 512; idx += 256) {
        int r = idx >> 3, g = idx & 7;
        uint4 v = {0, 0, 0, 0};
        if (r < rows) v = *(const uint4*)&Ab[(size_t)(row0 + r) * 64 + g * 8];
        *(uint4*)&As32[r * 36 + g * 4] = v;
    }
    for (int idx = threadIdx.x; idx < 32 * F; idx += 256) {
        int kp = idx / F, c = idx - kp * F;
        Ws32[c * 36 + kp] = pack2(W[(2 * kp) * F + c], W[(2 * kp + 1) * F + c]);
    }
    __syncthreads();
    int w = threadIdx.x >> 6, lane = threadIdx.x & 63, q = lane >> 4, ln = lane & 15;
    f32x4 acc[NC];
#pragma unroll
    for (int ct = 0; ct < NC; ++ct) acc[ct] = {0.f, 0.f, 0.f, 0.f};
#pragma unroll
    for (int s = 0; s < 2; ++s) {
        v8s af = *(const v8s*)&As32[(16 * w + ln) * 36 + s * 16 + q * 4];
#pragma unroll
        for (int ct = 0; ct < NC; ++ct) {
            v8s bfr = *(const v8s*)&Ws32[(ct * 16 + ln) * 36 + s * 16 + q * 4];
            acc[ct] = __builtin_amdgcn_mfma_f32_16x16x32_bf16(af, bfr, acc[ct], 0, 0, 0);
        }
    }
#pragma unroll
    for (int ct = 0; ct < NC; ++ct)
#pragma unroll
        for (int i = 0; i < 4; ++i) {
            int r = 16 * w + q * 4 + i;
            if (r < rows) C[(size_t)(row0 + r) * F + ct * 16 + ln] = acc[ct][i];
        }
}

// comb[lrow, slice*128 + c] (bf16) = san(bn(T) + h1b @ res_slice)
__global__ __launch_bounds__(256) void mfma_apply1(const unsigned short* __restrict__ h1b,
                                                   const float* __restrict__ T,
                                                   const float* __restrict__ res0,
                                                   const float* __restrict__ res1,
                                                   const float* __restrict__ scsh,
                                                   unsigned short* __restrict__ comb, int n) {
    __shared__ unsigned As32[64 * 36];
    __shared__ unsigned Ws32[128 * 36];
    int BPS = (n + 63) >> 6;
    int slice = blockIdx.x >= BPS;
    int sb = blockIdx.x - slice * BPS;
    const float* W = slice ? res1 : res0;
    int row0 = slice * n + sb * 64;
    int rows = min(64, n - sb * 64);
    for (int idx = threadIdx.x; idx < 512; idx += 256) {
        int r = idx >> 3, g = idx & 7;
        uint4 v = {0, 0, 0, 0};
        if (r < rows) v = *(const uint4*)&h1b[(size_t)(row0 + r) * 64 + g * 8];
        *(uint4*)&As32[r * 36 + g * 4] = v;
    }
    for (int idx = threadIdx.x; idx < 32 * 128; idx += 256) {
        int kp = idx >> 7, c = idx & 127;
        Ws32[c * 36 + kp] = pack2(W[(2 * kp) * 128 + c], W[(2 * kp + 1) * 128 + c]);
    }
    __syncthreads();
    int w = threadIdx.x >> 6, lane = threadIdx.x & 63, q = lane >> 4, ln = lane & 15;
    f32x4 acc[8];
#pragma unroll
    for (int ct = 0; ct < 8; ++ct) acc[ct] = {0.f, 0.f, 0.f, 0.f};
#pragma unroll
    for (int s = 0; s < 2; ++s) {
        v8s af = *(const v8s*)&As32[(16 * w + ln) * 36 + s * 16 + q * 4];
#pragma unroll
        for (int ct = 0; ct < 8; ++ct) {
            v8s bfr = *(const v8s*)&Ws32[(ct * 16 + ln) * 36 + s * 16 + q * 4];
            acc[ct] = __builtin_amdgcn_mfma_f32_16x16x32_bf16(af, bfr, acc[ct], 0, 0, 0);
        }
    }
    const float* sc = scsh + slice * 256;
#pragma unroll
    for (int ct = 0; ct < 8; ++ct) {
        int c = ct * 16 + ln;
        float scale = sc[c], shift = sc[128 + c];
#pragma unroll
        for (int i = 0; i < 4; ++i) {
            int r = 16 * w + q * 4 + i;
            if (r >= rows) continue;
            int row = row0 + r;
            float tv = T[(size_t)row * 128 + c];
            float o = sanf(fmaf(tv, scale, shift) + acc[ct][i]);
            comb[(size_t)(row - slice * n) * 256 + slice * 128 + c] = bf16of(o);
        }
    }
}

// hb[n,128] (bf16) = relu(comb[n,256] @ fc1[256,128] + bias); 4 k-tiles
__global__ __launch_bounds__(256) void mfma_head(const unsigned short* __restrict__ comb,
                                                 const float* __restrict__ W,
                                                 const float* __restrict__ bias,
                                                 unsigned short* __restrict__ hb, int n) {
    __shared__ unsigned As32[64 * 36];
    __shared__ unsigned Ws32[128 * 36];
    int row0 = blockIdx.x * 64;
    int rows = min(64, n - row0);
    int w = threadIdx.x >> 6, lane = threadIdx.x & 63, q = lane >> 4, ln = lane & 15;
    f32x4 acc[8];
#pragma unroll
    for (int ct = 0; ct < 8; ++ct) acc[ct] = {0.f, 0.f, 0.f, 0.f};
    for (int kt = 0; kt < 4; ++kt) {
        for (int idx = threadIdx.x; idx < 512; idx += 256) {
            int r = idx >> 3, g = idx & 7;
            uint4 v = {0, 0, 0, 0};
            if (r < rows) v = *(const uint4*)&comb[(size_t)(row0 + r) * 256 + kt * 64 + g * 8];
            *(uint4*)&As32[r * 36 + g * 4] = v;
        }
        for (int idx = threadIdx.x; idx < 32 * 128; idx += 256) {
            int kp = idx >> 7, c = idx & 127;
            Ws32[c * 36 + kp] =
                pack2(W[(size_t)(kt * 64 + 2 * kp) * 128 + c], W[(size_t)(kt * 64 + 2 * kp + 1) * 128 + c]);
        }
        __syncthreads();
#pragma unroll
        for (int s = 0; s < 2; ++s) {
            v8s af = *(const v8s*)&As32[(16 * w + ln) * 36 + s * 16 + q * 4];
#pragma unroll
            for (int ct = 0; ct < 8; ++ct) {
                v8s bfr = *(const v8s*)&Ws32[(ct * 16 + ln) * 36 + s * 16 + q * 4];
                acc[ct] = __builtin_amdgcn_mfma_f32_16x16x32_bf16(af, bfr, acc[ct], 0, 0, 0);
            }
        }
        __syncthreads();
    }
#pragma unroll
    for (int ct = 0; ct < 8; ++ct) {
        int c = ct * 16 + ln;
        float b = bias[c];
#pragma unroll
        for (int i = 0; i < 4; ++i) {
            int r = 16 * w + q * 4 + i;
            if (r >= rows) continue;
            float o = fmaxf(acc[ct][i] + b, 0.f);
            hb[(size_t)(row0 + r) * 128 + c] = bf16of(o);
        }
    }
}

// --- BN / pointwise ----------------------------------------------------------

template <int F>
__global__ __launch_bounds__(256) void bnstats_kernel(const float* __restrict__ h,
                                                      float* __restrict__ sums, int n, int bps) {
    constexpr int TPF = 256 / F;
    constexpr int ROWS = 128;
    __shared__ float l1[256], l2[256];
    int slice = blockIdx.x >= bps;
    int sb = blockIdx.x - slice * bps;
    int f = threadIdx.x & (F - 1);
    int sub = threadIdx.x / F;
    int r0 = slice * n + sb * ROWS;
    int rend = min(slice * n + n, r0 + ROWS);
    float s1 = 0.f, s2 = 0.f;
    for (int r = r0 + sub; r < rend; r += TPF) {
        float v = h[(size_t)r * F + f];
        s1 += v;
        s2 += v * v;
    }
    l1[threadIdx.x] = s1;
    l2[threadIdx.x] = s2;
    __syncthreads();
    if (threadIdx.x < F) {
#pragma unroll
        for (int i = 1; i < TPF; ++i) {
            s1 += l1[threadIdx.x + i * F];
            s2 += l2[threadIdx.x + i * F];
        }
        unsafeAtomicAdd(&sums[slice * 2 * F + threadIdx.x], s1);
        unsafeAtomicAdd(&sums[slice * 2 * F + F + threadIdx.x], s2);
    }
}

template <int F>
__global__ void bnfinal_kernel(const float* __restrict__ sums, const float* __restrict__ g,
                               const float* __restrict__ be, float* __restrict__ scsh, int n) {
    int f = threadIdx.x;
    if (f >= F) return;
    int slice = blockIdx.x;
    float inv_n = 1.0f / (float)n;
    float mu = sums[slice * 2 * F + f] * inv_n;
    float var = fmaxf(sums[slice * 2 * F + F + f] * inv_n - mu * mu, 0.f);
    float scale = g[f] * rsqrtf(var + 1e-5f);
    scsh[slice * 2 * F + f] = scale;
    scsh[slice * 2 * F + F + f] = be[f] - mu * scale;
}

// h1 = san(relu(bn(t0)) + x); h1b = bf16(h1); h1sb = bf16(dinv * h1)
__global__ __launch_bounds__(256) void apply0_kernel(const float* __restrict__ t0,
                                                     const float* __restrict__ x,
                                                     const float* __restrict__ scsh,
                                                     const float* __restrict__ dinv,
                                                     unsigned short* __restrict__ h1b,
                                                     unsigned short* __restrict__ h1sb,
                                                     int n64, int total) {
    int i = blockIdx.x * 256 + threadIdx.x;
    if (i >= total) return;
    int slice = i >= n64;
    int f = i & 63;
    const float* sc = scsh + slice * 128;
    float v = fmaf(t0[i], sc[f], sc[64 + f]);
    v = fmaxf(v, 0.f) + x[i - slice * n64];
    v = sanf(v);
    h1b[i] = bf16of(v);
    h1sb[i] = bf16of(v * dinv[i >> 6]);
}

__global__ __launch_bounds__(256) void fc2_softmax_kernel(const unsigned short* __restrict__ hb,
                                                          const float* __restrict__ w2,
                                                          const float* __restrict__ b2,
                                                          float* __restrict__ out, int n) {
    int gid = blockIdx.x * 256 + threadIdx.x;
    int row = gid >> 6;
    int lane = threadIdx.x & 63;
    if (row >= n) return;
    const unsigned short* hr = hb + (size_t)row * 128;
    float a = fofbf16(hr[lane]), b = fofbf16(hr[lane + 64]);
    float p0 = fmaf(a, w2[lane * 2], b * w2[(lane + 64) * 2]);
    float p1 = fmaf(a, w2[lane * 2 + 1], b * w2[(lane + 64) * 2 + 1]);
#pragma unroll
    for (int o = 32; o > 0; o >>= 1) {
        p0 += __shfl_down(p0, o);
        p1 += __shfl_down(p1, o);
    }
    if (lane == 0) {
        float l0 = p0 + b2[0], l1 = p1 + b2[1];
        float mx = fmaxf(l0, l1);
        float e0 = expf(l0 - mx), e1 = expf(l1 - mx);
        float inv = 1.0f / (e0 + e1);
        out[(size_t)row * 2] = l0;
        out[(size_t)row * 2 + 1] = l1;
        out[(size_t)2 * n + row * 2] = e0 * inv;
        out[(size_t)2 * n + row * 2 + 1] = e1 * inv;
    }
}

static inline int cdiv(int a, int b) { return (a + b - 1) / b; }

extern "C" void kernel_launch(void* const* d_in, const int* in_sizes, int n_in,
                              void* d_out, int out_size, void* d_ws, size_t ws_size,
                              hipStream_t stream) {
    const float* x       = (const float*)d_in[0];
    const int*   ei0     = (const int*)d_in[1];
    const int*   ei1     = (const int*)d_in[2];
    const float* w0_s0   = (const float*)d_in[3];
    const float* w1_s0   = (const float*)d_in[5];
    const float* res1_s0 = (const float*)d_in[7];
    const float* w0_s1   = (const float*)d_in[8];
    const float* w1_s1   = (const float*)d_in[10];
    const float* res1_s1 = (const float*)d_in[12];
    const float* bn_g0   = (const float*)d_in[13];
    const float* bn_b0   = (const float*)d_in[14];
    const float* bn_g1   = (const float*)d_in[15];
    const float* bn_b1   = (const float*)d_in[16];
    const float* fc1_w   = (const float*)d_in[17];
    const float* fc1_b   = (const float*)d_in[18];
    const float* fc2_w   = (const float*)d_in[19];
    const float* fc2_b   = (const float*)d_in[20];
    float* out = (float*)d_out;

    int n = in_sizes[0] / 64;   // 50000
    int E = in_sizes[1] / 2;    // 1600000
    int n2 = 2 * n, E2 = 2 * E;
    int n64 = n * 64;
    int NB = cdiv(n2, 256);     // 391 buckets
    int BPS = cdiv(n, 64);      // 782 row-tiles per slice

    // float-unit layout (all offsets 16B-aligned):
    // X1 fp32[2n*64] (t0; lower half of T) | S fp32[2n*64] (upper T; h1sb overlay)
    // Gb u16[2n*64] | h1b u16[2n*64] | comb u16[n*256] (binned u32 overlay)
    // hb u16[n*128] (xsb u16 overlay) | dinv[2n] | sums[512] | scsh[512] | ints
    float* X1 = (float*)d_ws;
    float* S  = X1 + (size_t)n2 * 64;
    float* T  = X1;                         // 2n x 128 fp32 spans X1+S
    unsigned short* Gb   = (unsigned short*)(S + (size_t)n2 * 64);
    unsigned short* h1b  = Gb + (size_t)n2 * 64;
    unsigned short* comb = h1b + (size_t)n2 * 64;
    unsigned short* hb   = comb + (size_t)n * 256;
    float* dinv = (float*)(hb + (size_t)n * 128);
    float* sums = dinv + n2;
    float* scsh = sums + 512;
    int* csr    = (int*)(scsh + 512);
    int* rowptr = csr + (size_t)E2;
    int* bcnt   = rowptr + (n2 + 1);
    int* bstart = bcnt + 512;
    int* bcur   = bstart + 513;
    unsigned* binned = (unsigned*)comb;          // dead before apply1 writes comb
    unsigned short* xsb  = (unsigned short*)hb;  // dead before head writes hb
    unsigned short* h1sb = (unsigned short*)S;   // dead before gemmb128 writes T

    // --- CSR build (2-pass bucket sort) ---
    hipMemsetAsync(bcnt, 0, 512 * sizeof(int), stream);
    kA_buckhist<<<256, 256, 0, stream>>>(ei0, ei1, bcnt, E, n, NB);
    kB_scan<<<1, 256, 0, stream>>>(bcnt, bstart, bcur, NB, E2);
    kC_bin<<<cdiv(E2, 8192), 256, 0, stream>>>(ei0, ei1, bcur, binned, E, n, 8192);
    kD_build<<<NB, 256, 0, stream>>>(binned, bstart, rowptr, dinv, csr, n2, E2);

    // --- layer 0: gather(bf16(dinv.x)) -> MFMA @W0 -> bn -> relu+x ---
    prescale_bf<<<cdiv(n64, 256), 256, 0, stream>>>(x, dinv, xsb, n64, n);
    gatherbf_kernel<<<cdiv(n2 * 8, 256), 256, 0, stream>>>(rowptr, csr, xsb, dinv, Gb, n, n2);
    mfma_gemmb<64><<<2 * BPS, 256, 0, stream>>>(Gb, w0_s0, w0_s1, X1, n);  // t0
    hipMemsetAsync(sums, 0, 256 * sizeof(float), stream);
    bnstats_kernel<64><<<2 * cdiv(n, 128), 256, 0, stream>>>(X1, sums, n, cdiv(n, 128));
    bnfinal_kernel<64><<<2, 64, 0, stream>>>(sums, bn_g0, bn_b0, scsh, n);
    apply0_kernel<<<cdiv(2 * n64, 256), 256, 0, stream>>>(X1, x, scsh, dinv, h1b, h1sb, n64, 2 * n64);

    // --- layer 1: gather(h1sb) -> MFMA @W1 -> bn ; MFMA h1b@res fused apply ---
    gatherbf_kernel<<<cdiv(n2 * 8, 256), 256, 0, stream>>>(rowptr, csr, h1sb, dinv, Gb, n, n2);
    mfma_gemmb<128><<<2 * BPS, 256, 0, stream>>>(Gb, w1_s0, w1_s1, T, n);  // t1
    hipMemsetAsync(sums, 0, 512 * sizeof(float), stream);
    bnstats_kernel<128><<<2 * cdiv(n, 128), 256, 0, stream>>>(T, sums, n, cdiv(n, 128));
    bnfinal_kernel<128><<<2, 128, 0, stream>>>(sums, bn_g1, bn_b1, scsh, n);
    mfma_apply1<<<2 * BPS, 256, 0, stream>>>(h1b, T, res1_s0, res1_s1, scsh, comb, n);

    // --- head ---
    mfma_head<<<BPS, 256, 0, stream>>>(comb, fc1_w, fc1_b, hb, n);
    fc2_softmax_kernel<<<cdiv(n, 4), 256, 0, stream>>>(hb, fc2_w, fc2_b, out, n);
}